// Round 9
// baseline (728.784 us; speedup 1.0000x reference)
//
#include <hip/hip_runtime.h>
#include <hip/hip_bf16.h>

// GraphConvLayer: out = relu(A_norm @ (X@W + b))
// Reassociated: Y = A@X (sparse, ~22.5 nnz/row), out = relu(Y@W + rowsum(A)[n]*b[d])
// x: [1024,543,256] f32; W: [256,256] f32; b: [256]; A: [543,543] f32; out: [1024,543,256] f32
//
// R9 = R8 (traffic-ideal, no spill) + latency amortization:
//  - 2 bt's per block: CSR entry s_loads shared, 16 x-loads in flight, 2x MFMA per block
//  - entry software prefetch (next quad's entries load during current FMAs; SGPR-only)
//  - LDS: Y for 2 bts (64KB); epilogue bounce overlays Y0 after barrier -> 2 blocks/CU

#define NND    543
#define NROWP  640
#define RPB    64           // rows per block
#define NTILES 9            // tiles per bt
#define NBT    2            // bts per block
#define CAPR   64           // CSR slots per row (mean ~22.5)
#define ESTRIDE 68          // CAPR + 4 zero slots for prefetch overrun
#define BTOT   1024
#define GRID   ((BTOT/NBT)*NTILES)   // 4608, %8==0 -> bijective XCD swizzle

typedef __attribute__((ext_vector_type(8))) short short8;
typedef __attribute__((ext_vector_type(4))) float f32x4;

// ---- workspace (bytes) ----
#define WS_ENT 0                          // uint2[640][68] = 348160 {m, f32bits(a)}, zero-padded
#define WS_CNT 348160                     // u32[640]: padded-to-4 count (<=CAPR) or ~0 = overflow
#define WS_RS  350720                     // f32[640] rowsum
#define WS_W   353280                     // bf16 frags [16][8][64][8] = 131072
#define WS_NEED 484352

// ---- LDS (bytes) ----
#define L_Y0   0                          // Y bt0 bf16 [64][512B] XOR-swz; bounce overlays after acc0
#define L_Y1   32768                      // Y bt1
#define L_RS   65536                      // f32[64]
#define L_TOT  65792                      // 64.25 KB -> 2 blocks/CU

__device__ __forceinline__ unsigned short f2bf(float f) {   // RNE f32 -> bf16 bits
  unsigned int u = __builtin_bit_cast(unsigned int, f);
  u += 0x7fffu + ((u >> 16) & 1u);
  return (unsigned short)(u >> 16);
}
__device__ __forceinline__ uint2 pack4(const f32x4 v) {
  uint2 u;
  u.x = (unsigned)f2bf(v.x) | ((unsigned)f2bf(v.y) << 16);
  u.y = (unsigned)f2bf(v.z) | ((unsigned)f2bf(v.w) << 16);
  return u;
}
__device__ __forceinline__ float bc(unsigned u) { return __builtin_bit_cast(float, u); }

// ---------------- prep: flat CSR zero-padded to ESTRIDE + rowsum (one wave/row) ----------------
__global__ void prep_csr(const float* __restrict__ A, char* __restrict__ ws) {
  const int wid = (blockIdx.x * blockDim.x + threadIdx.x) >> 6;
  const int lane = threadIdx.x & 63;
  if (wid >= NROWP) return;
  uint2* ep = (uint2*)(ws + WS_ENT) + (size_t)wid * ESTRIDE;
  unsigned* cw = (unsigned*)(ws + WS_CNT);
  float* rs = (float*)(ws + WS_RS);
  if (wid >= NND) {
    for (int k = lane; k < ESTRIDE; k += 64) ep[k] = make_uint2(0u, 0u);
    if (lane == 0) { cw[wid] = 0u; rs[wid] = 0.f; }
    return;
  }
  const float* arow = A + (size_t)wid * NND;
  float s = 0.f; int cnt = 0;
  for (int m0 = 0; m0 < NND; m0 += 64) {
    const int m = m0 + lane;
    const float a = (m < NND) ? arow[m] : 0.f;
    s += a;
    const unsigned long long mask = __ballot(a != 0.f);
    if (a != 0.f) {
      const int idx = cnt + (int)__popcll(mask & ((1ull << lane) - 1ull));
      if (idx < CAPR) ep[idx] = make_uint2((unsigned)m, __builtin_bit_cast(unsigned, a));
    }
    cnt += (int)__popcll(mask);
  }
  #pragma unroll
  for (int o = 32; o > 0; o >>= 1) s += __shfl_xor(s, o);
  if (cnt <= CAPR) {                       // zero-pad to ESTRIDE: {m=0, a=0} is harmless
    for (int k = cnt + lane; k < ESTRIDE; k += 64) ep[k] = make_uint2(0u, 0u);
  }
  if (lane == 0) {
    cw[wid] = (cnt <= CAPR) ? (unsigned)((cnt + 3) & ~3) : 0xFFFFFFFFu;
    rs[wid] = s;
  }
}

// ---------------- prep: W -> bf16 MFMA B-fragments [g][ks][lane][8], g = col/16 ----------------
__global__ void prep_w(const float* __restrict__ W, char* __restrict__ ws) {
  const int t = blockIdx.x * 256 + threadIdx.x;
  if (t >= 16 * 8 * 64) return;
  const int lane = t & 63, ks = (t >> 6) & 7, g = t >> 9;
  const int krow = (lane >> 4) * 8, col = g * 16 + (lane & 15);
  unsigned short* dst = (unsigned short*)(ws + WS_W) + (size_t)t * 8;
  #pragma unroll
  for (int e = 0; e < 8; e++) dst[e] = f2bf(W[(ks * 32 + krow + e) * 256 + col]);
}

// one row, one bt: sparse-if-fits else dense (rare overflow path)
__device__ __forceinline__ void gather_one(const uint2* __restrict__ entp, const unsigned cnt,
                                           const float* __restrict__ A,
                                           const float* __restrict__ xbt,
                                           const int n, const int lane, f32x4& y) {
  if (cnt <= CAPR) {
    const uint2* ep = entp + (size_t)n * ESTRIDE;
    for (unsigned j = 0; j < cnt; ++j) {
      const uint2 e = ep[j];
      y += bc(e.y) * *(const f32x4*)(xbt + (e.x << 8) + (lane << 2));
    }
  } else if (n < NND) {
    const float* arow = A + (size_t)n * NND;
    for (int m = 0; m < NND; ++m) {
      const float a = arow[m];
      if (a != 0.f) y += a * *(const f32x4*)(xbt + (m << 8) + (lane << 2));
    }
  }
}

// ---------------- main ----------------
__global__ __launch_bounds__(512, 2)   // 128 VGPR cap (2nd arg = blocks/CU, empirical)
void gcn_main(const float* __restrict__ x, const float* __restrict__ Wm,
              const float* __restrict__ bias, const float* __restrict__ A,
              float* __restrict__ out, const char* __restrict__ ws, int use_ws)
{
  __shared__ __align__(16) char lds[L_TOT];
  float* rsl = (float*)(lds + L_RS);

  const int tid = threadIdx.x;
  const int w = tid >> 6, lane = tid & 63;
  const int cl = lane & 15, krow = (lane >> 4) * 8;

  // XCD swizzle: the 9 tiles of one bt-pair adjacent -> co-resident on one XCD
  const int p = blockIdx.x;
  const int L = (p & 7) * (GRID / 8) + (p >> 3);
  const int btp = L / NTILES;
  const int tile = L - btp * NTILES;
  const int n0 = tile * RPB;
  const int bt0 = btp * 2;

  const float* xb0 = x + (size_t)bt0 * (NND * 256);
  const float* xb1 = xb0 + NND * 256;
  const uint2* entp = (const uint2*)(ws + WS_ENT);
  const unsigned* cnts = (const unsigned*)(ws + WS_CNT);

  if (tid < RPB) rsl[tid] = use_ws ? ((const float*)(ws + WS_RS))[n0 + tid] : 0.f;

  // ---- gather: 2 rows x 2 bts in flight; shared entry s_loads + entry prefetch ----
  for (int rr = 0; rr < 8; rr += 2) {
    const int r0 = w * 8 + rr;
    const int nA = __builtin_amdgcn_readfirstlane(n0 + r0);     // wave-uniform
    const int nB = nA + 1;
    f32x4 yA0 = (f32x4){0.f,0.f,0.f,0.f}, yB0 = yA0, yA1 = yA0, yB1 = yA0;

    if (use_ws) {
      const unsigned cA = cnts[nA], cB = cnts[nB];
      if (cA <= CAPR && cB <= CAPR) {
        const unsigned cm = cA > cB ? cA : cB;                  // rows zero-padded -> safe
        const uint2* epA = entp + (size_t)nA * ESTRIDE;
        const uint2* epB = entp + (size_t)nB * ESTRIDE;
        uint2 a0 = epA[0], a1 = epA[1], a2 = epA[2], a3 = epA[3];
        uint2 b0 = epB[0], b1 = epB[1], b2 = epB[2], b3 = epB[3];
        for (unsigned j = 0; j < cm; j += 4) {
          // 16 x-loads in flight (2 rows x 4 entries x 2 bts)
          const f32x4 xa00 = *(const f32x4*)(xb0 + (a0.x << 8) + (lane << 2));
          const f32x4 xa10 = *(const f32x4*)(xb0 + (a1.x << 8) + (lane << 2));
          const f32x4 xa20 = *(const f32x4*)(xb0 + (a2.x << 8) + (lane << 2));
          const f32x4 xa30 = *(const f32x4*)(xb0 + (a3.x << 8) + (lane << 2));
          const f32x4 xb00 = *(const f32x4*)(xb0 + (b0.x << 8) + (lane << 2));
          const f32x4 xb10 = *(const f32x4*)(xb0 + (b1.x << 8) + (lane << 2));
          const f32x4 xb20 = *(const f32x4*)(xb0 + (b2.x << 8) + (lane << 2));
          const f32x4 xb30 = *(const f32x4*)(xb0 + (b3.x << 8) + (lane << 2));
          const f32x4 xa01 = *(const f32x4*)(xb1 + (a0.x << 8) + (lane << 2));
          const f32x4 xa11 = *(const f32x4*)(xb1 + (a1.x << 8) + (lane << 2));
          const f32x4 xa21 = *(const f32x4*)(xb1 + (a2.x << 8) + (lane << 2));
          const f32x4 xa31 = *(const f32x4*)(xb1 + (a3.x << 8) + (lane << 2));
          const f32x4 xb01 = *(const f32x4*)(xb1 + (b0.x << 8) + (lane << 2));
          const f32x4 xb11 = *(const f32x4*)(xb1 + (b1.x << 8) + (lane << 2));
          const f32x4 xb21 = *(const f32x4*)(xb1 + (b2.x << 8) + (lane << 2));
          const f32x4 xb31 = *(const f32x4*)(xb1 + (b3.x << 8) + (lane << 2));
          // prefetch next quad's entries (SGPR; slots cm..cm+3 are zero pad)
          const uint2 pa0 = epA[j+4], pa1 = epA[j+5], pa2 = epA[j+6], pa3 = epA[j+7];
          const uint2 pb0 = epB[j+4], pb1 = epB[j+5], pb2 = epB[j+6], pb3 = epB[j+7];
          yA0 += bc(a0.y) * xa00;  yA0 += bc(a1.y) * xa10;
          yA0 += bc(a2.y) * xa20;  yA0 += bc(a3.y) * xa30;
          yB0 += bc(b0.y) * xb00;  yB0 += bc(b1.y) * xb10;
          yB0 += bc(b2.y) * xb20;  yB0 += bc(b3.y) * xb30;
          yA1 += bc(a0.y) * xa01;  yA1 += bc(a1.y) * xa11;
          yA1 += bc(a2.y) * xa21;  yA1 += bc(a3.y) * xa31;
          yB1 += bc(b0.y) * xb01;  yB1 += bc(b1.y) * xb11;
          yB1 += bc(b2.y) * xb21;  yB1 += bc(b3.y) * xb31;
          a0 = pa0; a1 = pa1; a2 = pa2; a3 = pa3;
          b0 = pb0; b1 = pb1; b2 = pb2; b3 = pb3;
        }
      } else {                                                  // rare overflow rows
        gather_one(entp, cA, A, xb0, nA, lane, yA0);
        gather_one(entp, cB, A, xb0, nB, lane, yB0);
        gather_one(entp, cA, A, xb1, nA, lane, yA1);
        gather_one(entp, cB, A, xb1, nB, lane, yB1);
      }
    } else {                                                    // no-ws fallback
      if (nA < NND) {
        const float* arow = A + (size_t)nA * NND;
        float s = 0.f;
        for (int m = 0; m < NND; ++m) {
          const float a = arow[m];
          s += a;
          if (a != 0.f) {
            yA0 += a * *(const f32x4*)(xb0 + (m << 8) + (lane << 2));
            yA1 += a * *(const f32x4*)(xb1 + (m << 8) + (lane << 2));
          }
        }
        if (lane == 0) rsl[r0] = s;
      }
      if (nB < NND) {
        const float* arow = A + (size_t)nB * NND;
        float s = 0.f;
        for (int m = 0; m < NND; ++m) {
          const float a = arow[m];
          s += a;
          if (a != 0.f) {
            yB0 += a * *(const f32x4*)(xb0 + (m << 8) + (lane << 2));
            yB1 += a * *(const f32x4*)(xb1 + (m << 8) + (lane << 2));
          }
        }
        if (lane == 0) rsl[r0 + 1] = s;
      }
    }

    // Y rows -> LDS bf16, XOR-swizzled
    const int s0 = (lane * 8) ^ ((r0 & 7) << 4);
    const int s1 = (lane * 8) ^ (((r0 + 1) & 7) << 4);
    *(uint2*)(lds + L_Y0 + r0 * 512 + s0)       = pack4(yA0);
    *(uint2*)(lds + L_Y0 + (r0+1) * 512 + s1)   = pack4(yB0);
    *(uint2*)(lds + L_Y1 + r0 * 512 + s0)       = pack4(yA1);
    *(uint2*)(lds + L_Y1 + (r0+1) * 512 + s1)   = pack4(yB1);
  }
  __syncthreads();

  // ---- W fragments: wave w owns cols [w*32, w*32+32) -> groups 2w, 2w+1 ----
  const int gA = 2 * w;
  short8 wfA[8], wfB[8];
  if (use_ws) {
    #pragma unroll
    for (int ks = 0; ks < 8; ++ks) {
      wfA[ks] = *(const short8*)(ws + WS_W + (size_t)(((gA * 8 + ks) * 64 + lane) << 4));
      wfB[ks] = *(const short8*)(ws + WS_W + (size_t)((((gA + 1) * 8 + ks) * 64 + lane) << 4));
    }
  } else {
    #pragma unroll
    for (int ks = 0; ks < 8; ++ks) {
      #pragma unroll
      for (int e = 0; e < 8; ++e) {
        wfA[ks][e] = (short)f2bf(Wm[(ks * 32 + krow + e) * 256 + gA * 16 + cl]);
        wfB[ks][e] = (short)f2bf(Wm[(ks * 32 + krow + e) * 256 + (gA + 1) * 16 + cl]);
      }
    }
  }

  const int dA = w * 32 + cl;
  const float bvA = bias[dA], bvB = bias[dA + 16];
  float* wb = (float*)(lds + L_Y0) + w * (16 * 36);   // bounce overlays Y0 (after acc0 barrier)

  #pragma unroll
  for (int bti = 0; bti < 2; ++bti) {
    const char* yb = lds + (bti ? L_Y1 : L_Y0);
    f32x4 accA[4], accB[4];
    #pragma unroll
    for (int mt = 0; mt < 4; ++mt) {
      accA[mt] = (f32x4){0.f,0.f,0.f,0.f};
      accB[mt] = (f32x4){0.f,0.f,0.f,0.f};
    }
    #pragma unroll
    for (int ks = 0; ks < 8; ++ks) {
      #pragma unroll
      for (int mt = 0; mt < 4; ++mt) {
        const int r = mt * 16 + cl;
        const int kb = (ks * 64 + krow * 2) ^ ((r & 7) << 4);
        const short8 af = *(const short8*)(yb + r * 512 + kb);
        accA[mt] = __builtin_amdgcn_mfma_f32_16x16x32_bf16(af, wfA[ks], accA[mt], 0, 0, 0);
        accB[mt] = __builtin_amdgcn_mfma_f32_16x16x32_bf16(af, wfB[ks], accB[mt], 0, 0, 0);
      }
    }
    if (bti == 0) __syncthreads();   // all waves done reading Y0 -> bounce may overlay it

    const size_t obase = ((size_t)(bt0 + bti) * NND) * 256;
    #pragma unroll
    for (int mt = 0; mt < 4; ++mt) {
      #pragma unroll
      for (int q = 0; q < 4; ++q) {
        const int r16 = (lane >> 4) * 4 + q;           // C/D: col=lane&15, row=(lane>>4)*4+q
        const float rsv = rsl[mt * 16 + r16];
        wb[r16 * 36 + cl]      = fmaxf(accA[mt][q] + rsv * bvA, 0.f);
        wb[r16 * 36 + 16 + cl] = fmaxf(accB[mt][q] + rsv * bvB, 0.f);
      }
      asm volatile("s_waitcnt lgkmcnt(0)" ::: "memory");  // wave-lockstep visibility
      #pragma unroll
      for (int v = 0; v < 2; ++v) {
        const int i = lane * 2 + v;                    // 128 vec4 slots of the 16x32 tile
        const int rI = i >> 3, cv = i & 7;
        const int n = n0 + mt * 16 + rI;
        if (n < NND)
          *(f32x4*)(out + obase + (size_t)n * 256 + w * 32 + cv * 4) =
              *(const f32x4*)(wb + rI * 36 + cv * 4);
      }
    }
  }
}

extern "C" void kernel_launch(void* const* d_in, const int* in_sizes, int n_in,
                              void* d_out, int out_size, void* d_ws, size_t ws_size,
                              hipStream_t stream) {
  const float* x  = (const float*)d_in[0];
  const float* Wm = (const float*)d_in[1];
  const float* b  = (const float*)d_in[2];
  const float* A  = (const float*)d_in[3];
  float* out = (float*)d_out;
  const int use_ws = (d_ws != nullptr && ws_size >= (size_t)WS_NEED) ? 1 : 0;
  if (use_ws) {
    prep_csr<<<(NROWP * 64 + 255) / 256, 256, 0, stream>>>(A, (char*)d_ws);
    prep_w<<<(16 * 8 * 64 + 255) / 256, 256, 0, stream>>>(Wm, (char*)d_ws);
  }
  gcn_main<<<GRID, 512, 0, stream>>>(x, Wm, b, A, out, (const char*)d_ws, use_ws);
}

// Round 10
// 713.115 us; speedup vs baseline: 1.0220x; 1.0220x over previous
//
#include <hip/hip_runtime.h>
#include <hip/hip_bf16.h>

// GraphConvLayer: out = relu(A_norm @ (X@W + b))
// Reassociated: Y = A@X (sparse, ~22.5 nnz/row), out = relu(Y@W + rowsum(A)[n]*b[d])
// x: [1024,543,256] f32; W: [256,256] f32; b: [256]; A: [543,543] f32; out: [1024,543,256] f32
//
// R10 = R8 (best: 691us, traffic-ideal, 51KB LDS -> 2 blocks/CU) + latency fixes:
//  - entry SGPR prefetch across quad-iterations (R9-proven; ESTRIDE=68 zero-pad)
//  - 4-row x 4-entry ILP: 16 x-loads in flight (R9 proved the reg budget: ~110 < 128)
//  - LDS kept at 51.4KB (R9 lesson: usable LDS/CU ~= 128KB; 66KB LDS -> 1 block/CU cliff)

#define NND    543
#define NROWP  640
#define RPB    64           // rows per block
#define NTILES 9            // tiles per bt
#define CAPR   64           // CSR slots per row (mean ~22.5)
#define ESTRIDE 68          // CAPR + 4 zero slots for prefetch overrun
#define BTOT   1024
#define GRID   (BTOT*NTILES)   // 9216, %8==0 -> bijective XCD swizzle

typedef __attribute__((ext_vector_type(8))) short short8;
typedef __attribute__((ext_vector_type(4))) float f32x4;

// ---- workspace (bytes) ----
#define WS_ENT 0                          // uint2[640][68] = 348160 {m, f32bits(a)}, zero-padded
#define WS_CNT 348160                     // u32[640]: padded-to-4 count (<=CAPR) or ~0 = overflow
#define WS_RS  350720                     // f32[640] rowsum
#define WS_W   353280                     // bf16 frags [16][8][64][8] = 131072
#define WS_NEED 484352

// ---- LDS (bytes) ----
#define L_Y    0                          // Y bf16 [64 rows][512B], XOR-swizzled = 32768
#define L_BNC  32768                      // per-wave bounce: 8 * 16*36*4 = 18432
#define L_RS   51200                      // f32[64]
#define L_TOT  51456                      // 50.2 KB -> 2 blocks/CU (128KB usable)

__device__ __forceinline__ unsigned short f2bf(float f) {   // RNE f32 -> bf16 bits
  unsigned int u = __builtin_bit_cast(unsigned int, f);
  u += 0x7fffu + ((u >> 16) & 1u);
  return (unsigned short)(u >> 16);
}
__device__ __forceinline__ uint2 pack4(const f32x4 v) {
  uint2 u;
  u.x = (unsigned)f2bf(v.x) | ((unsigned)f2bf(v.y) << 16);
  u.y = (unsigned)f2bf(v.z) | ((unsigned)f2bf(v.w) << 16);
  return u;
}
__device__ __forceinline__ float bc(unsigned u) { return __builtin_bit_cast(float, u); }

// ---------------- prep: flat CSR zero-padded to ESTRIDE + rowsum (one wave/row) ----------------
__global__ void prep_csr(const float* __restrict__ A, char* __restrict__ ws) {
  const int wid = (blockIdx.x * blockDim.x + threadIdx.x) >> 6;
  const int lane = threadIdx.x & 63;
  if (wid >= NROWP) return;
  uint2* ep = (uint2*)(ws + WS_ENT) + (size_t)wid * ESTRIDE;
  unsigned* cw = (unsigned*)(ws + WS_CNT);
  float* rs = (float*)(ws + WS_RS);
  if (wid >= NND) {
    for (int k = lane; k < ESTRIDE; k += 64) ep[k] = make_uint2(0u, 0u);
    if (lane == 0) { cw[wid] = 0u; rs[wid] = 0.f; }
    return;
  }
  const float* arow = A + (size_t)wid * NND;
  float s = 0.f; int cnt = 0;
  for (int m0 = 0; m0 < NND; m0 += 64) {
    const int m = m0 + lane;
    const float a = (m < NND) ? arow[m] : 0.f;
    s += a;
    const unsigned long long mask = __ballot(a != 0.f);
    if (a != 0.f) {
      const int idx = cnt + (int)__popcll(mask & ((1ull << lane) - 1ull));
      if (idx < CAPR) ep[idx] = make_uint2((unsigned)m, __builtin_bit_cast(unsigned, a));
    }
    cnt += (int)__popcll(mask);
  }
  #pragma unroll
  for (int o = 32; o > 0; o >>= 1) s += __shfl_xor(s, o);
  if (cnt <= CAPR) {                       // zero-pad to ESTRIDE: {m=0, a=0} is harmless
    for (int k = cnt + lane; k < ESTRIDE; k += 64) ep[k] = make_uint2(0u, 0u);
  }
  if (lane == 0) {
    cw[wid] = (cnt <= CAPR) ? (unsigned)((cnt + 3) & ~3) : 0xFFFFFFFFu;
    rs[wid] = s;
  }
}

// ---------------- prep: W -> bf16 MFMA B-fragments [g][ks][lane][8], g = col/16 ----------------
__global__ void prep_w(const float* __restrict__ W, char* __restrict__ ws) {
  const int t = blockIdx.x * 256 + threadIdx.x;
  if (t >= 16 * 8 * 64) return;
  const int lane = t & 63, ks = (t >> 6) & 7, g = t >> 9;
  const int krow = (lane >> 4) * 8, col = g * 16 + (lane & 15);
  unsigned short* dst = (unsigned short*)(ws + WS_W) + (size_t)t * 8;
  #pragma unroll
  for (int e = 0; e < 8; e++) dst[e] = f2bf(W[(ks * 32 + krow + e) * 256 + col]);
}

// one row: sparse-if-fits else dense (rare overflow path)
__device__ __forceinline__ void gather_one(const uint2* __restrict__ entp, const unsigned cnt,
                                           const float* __restrict__ A,
                                           const float* __restrict__ xbt,
                                           const int n, const int lane, f32x4& y) {
  if (cnt <= CAPR) {
    const uint2* ep = entp + (size_t)n * ESTRIDE;
    for (unsigned j = 0; j < cnt; ++j) {
      const uint2 e = ep[j];
      y += bc(e.y) * *(const f32x4*)(xbt + (e.x << 8) + (lane << 2));
    }
  } else if (n < NND) {
    const float* arow = A + (size_t)n * NND;
    for (int m = 0; m < NND; ++m) {
      const float a = arow[m];
      if (a != 0.f) y += a * *(const f32x4*)(xbt + (m << 8) + (lane << 2));
    }
  }
}

// ---------------- main ----------------
__global__ __launch_bounds__(512, 2)   // 16 waves/CU, 128 VGPR cap (empirical rule)
void gcn_main(const float* __restrict__ x, const float* __restrict__ Wm,
              const float* __restrict__ bias, const float* __restrict__ A,
              float* __restrict__ out, const char* __restrict__ ws, int use_ws)
{
  __shared__ __align__(16) char lds[L_TOT];
  float* rsl = (float*)(lds + L_RS);

  const int tid = threadIdx.x;
  const int w = tid >> 6, lane = tid & 63;
  const int cl = lane & 15, krow = (lane >> 4) * 8;

  // XCD swizzle: the 9 tiles of one bt adjacent -> co-resident on one XCD
  const int p = blockIdx.x;
  const int L = (p & 7) * (GRID / 8) + (p >> 3);
  const int bt = L / NTILES;
  const int tile = L - bt * NTILES;
  const int n0 = tile * RPB;

  const float* xbt = x + (size_t)bt * (NND * 256);
  const uint2* entp = (const uint2*)(ws + WS_ENT);
  const unsigned* cnts = (const unsigned*)(ws + WS_CNT);

  if (tid < RPB) rsl[tid] = use_ws ? ((const float*)(ws + WS_RS))[n0 + tid] : 0.f;

  // ---- gather: 4 rows x 4 entries in flight (16 x-loads) + entry SGPR prefetch ----
  for (int rr = 0; rr < 8; rr += 4) {
    const int r0 = w * 8 + rr;
    const int nA = __builtin_amdgcn_readfirstlane(n0 + r0);    // wave-uniform
    f32x4 y0 = (f32x4){0.f,0.f,0.f,0.f}, y1 = y0, y2 = y0, y3 = y0;

    if (use_ws) {
      const unsigned c0 = cnts[nA], c1 = cnts[nA+1], c2 = cnts[nA+2], c3 = cnts[nA+3];
      unsigned cm = c0 > c1 ? c0 : c1;
      cm = cm > c2 ? cm : c2;  cm = cm > c3 ? cm : c3;
      if (cm <= CAPR) {
        const uint2* e0p = entp + (size_t)nA * ESTRIDE;
        const uint2* e1p = e0p + ESTRIDE;
        const uint2* e2p = e1p + ESTRIDE;
        const uint2* e3p = e2p + ESTRIDE;
        uint2 a0 = e0p[0], a1 = e0p[1], a2 = e0p[2], a3 = e0p[3];
        uint2 b0 = e1p[0], b1 = e1p[1], b2 = e1p[2], b3 = e1p[3];
        uint2 c0e = e2p[0], c1e = e2p[1], c2e = e2p[2], c3e = e2p[3];
        uint2 d0 = e3p[0], d1 = e3p[1], d2 = e3p[2], d3 = e3p[3];
        for (unsigned j = 0; j < cm; j += 4) {
          // 16 x-loads in flight
          const f32x4 xa0 = *(const f32x4*)(xbt + (a0.x << 8) + (lane << 2));
          const f32x4 xa1 = *(const f32x4*)(xbt + (a1.x << 8) + (lane << 2));
          const f32x4 xa2 = *(const f32x4*)(xbt + (a2.x << 8) + (lane << 2));
          const f32x4 xa3 = *(const f32x4*)(xbt + (a3.x << 8) + (lane << 2));
          const f32x4 xb0 = *(const f32x4*)(xbt + (b0.x << 8) + (lane << 2));
          const f32x4 xb1 = *(const f32x4*)(xbt + (b1.x << 8) + (lane << 2));
          const f32x4 xb2 = *(const f32x4*)(xbt + (b2.x << 8) + (lane << 2));
          const f32x4 xb3 = *(const f32x4*)(xbt + (b3.x << 8) + (lane << 2));
          const f32x4 xc0 = *(const f32x4*)(xbt + (c0e.x << 8) + (lane << 2));
          const f32x4 xc1 = *(const f32x4*)(xbt + (c1e.x << 8) + (lane << 2));
          const f32x4 xc2 = *(const f32x4*)(xbt + (c2e.x << 8) + (lane << 2));
          const f32x4 xc3 = *(const f32x4*)(xbt + (c3e.x << 8) + (lane << 2));
          const f32x4 xd0 = *(const f32x4*)(xbt + (d0.x << 8) + (lane << 2));
          const f32x4 xd1 = *(const f32x4*)(xbt + (d1.x << 8) + (lane << 2));
          const f32x4 xd2 = *(const f32x4*)(xbt + (d2.x << 8) + (lane << 2));
          const f32x4 xd3 = *(const f32x4*)(xbt + (d3.x << 8) + (lane << 2));
          // prefetch next quad's entries (SGPR; slots cm..cm+3 are zero pad)
          const uint2 pa0 = e0p[j+4], pa1 = e0p[j+5], pa2 = e0p[j+6], pa3 = e0p[j+7];
          const uint2 pb0 = e1p[j+4], pb1 = e1p[j+5], pb2 = e1p[j+6], pb3 = e1p[j+7];
          const uint2 pc0 = e2p[j+4], pc1 = e2p[j+5], pc2 = e2p[j+6], pc3 = e2p[j+7];
          const uint2 pd0 = e3p[j+4], pd1 = e3p[j+5], pd2 = e3p[j+6], pd3 = e3p[j+7];
          y0 += bc(a0.y) * xa0;  y0 += bc(a1.y) * xa1;
          y0 += bc(a2.y) * xa2;  y0 += bc(a3.y) * xa3;
          y1 += bc(b0.y) * xb0;  y1 += bc(b1.y) * xb1;
          y1 += bc(b2.y) * xb2;  y1 += bc(b3.y) * xb3;
          y2 += bc(c0e.y) * xc0; y2 += bc(c1e.y) * xc1;
          y2 += bc(c2e.y) * xc2; y2 += bc(c3e.y) * xc3;
          y3 += bc(d0.y) * xd0;  y3 += bc(d1.y) * xd1;
          y3 += bc(d2.y) * xd2;  y3 += bc(d3.y) * xd3;
          a0 = pa0; a1 = pa1; a2 = pa2; a3 = pa3;
          b0 = pb0; b1 = pb1; b2 = pb2; b3 = pb3;
          c0e = pc0; c1e = pc1; c2e = pc2; c3e = pc3;
          d0 = pd0; d1 = pd1; d2 = pd2; d3 = pd3;
        }
      } else {                                                  // rare overflow rows
        gather_one(entp, c0, A, xbt, nA,     lane, y0);
        gather_one(entp, c1, A, xbt, nA + 1, lane, y1);
        gather_one(entp, c2, A, xbt, nA + 2, lane, y2);
        gather_one(entp, c3, A, xbt, nA + 3, lane, y3);
      }
    } else {                                                    // no-ws fallback
      #pragma unroll
      for (int q = 0; q < 4; ++q) {
        const int n = nA + q;
        if (n < NND) {
          const float* arow = A + (size_t)n * NND;
          float s = 0.f;
          f32x4 yv = (f32x4){0.f,0.f,0.f,0.f};
          for (int m = 0; m < NND; ++m) {
            const float a = arow[m];
            s += a;
            if (a != 0.f) yv += a * *(const f32x4*)(xbt + (m << 8) + (lane << 2));
          }
          if (q == 0) y0 = yv; else if (q == 1) y1 = yv;
          else if (q == 2) y2 = yv; else y3 = yv;
          if (lane == 0) rsl[r0 + q] = s;
        }
      }
    }

    // Y rows -> LDS bf16, XOR-swizzled
    *(uint2*)(lds + (r0+0) * 512 + ((lane * 8) ^ (((r0+0) & 7) << 4))) = pack4(y0);
    *(uint2*)(lds + (r0+1) * 512 + ((lane * 8) ^ (((r0+1) & 7) << 4))) = pack4(y1);
    *(uint2*)(lds + (r0+2) * 512 + ((lane * 8) ^ (((r0+2) & 7) << 4))) = pack4(y2);
    *(uint2*)(lds + (r0+3) * 512 + ((lane * 8) ^ (((r0+3) & 7) << 4))) = pack4(y3);
  }
  __syncthreads();

  // ---- MFMA: wave w owns cols [w*32, w*32+32): groups gA=2w, gA+1 ----
  const int gA = 2 * w;
  short8 wfA[8], wfB[8];
  if (use_ws) {
    #pragma unroll
    for (int ks = 0; ks < 8; ++ks) {
      wfA[ks] = *(const short8*)(ws + WS_W + (size_t)(((gA * 8 + ks) * 64 + lane) << 4));
      wfB[ks] = *(const short8*)(ws + WS_W + (size_t)((((gA + 1) * 8 + ks) * 64 + lane) << 4));
    }
  } else {
    #pragma unroll
    for (int ks = 0; ks < 8; ++ks) {
      #pragma unroll
      for (int e = 0; e < 8; ++e) {
        wfA[ks][e] = (short)f2bf(Wm[(ks * 32 + krow + e) * 256 + gA * 16 + cl]);
        wfB[ks][e] = (short)f2bf(Wm[(ks * 32 + krow + e) * 256 + (gA + 1) * 16 + cl]);
      }
    }
  }
  f32x4 accA[4], accB[4];
  #pragma unroll
  for (int mt = 0; mt < 4; ++mt) {
    accA[mt] = (f32x4){0.f, 0.f, 0.f, 0.f};
    accB[mt] = (f32x4){0.f, 0.f, 0.f, 0.f};
  }
  #pragma unroll
  for (int ks = 0; ks < 8; ++ks) {
    #pragma unroll
    for (int mt = 0; mt < 4; ++mt) {
      const int r = mt * 16 + cl;
      const int kb = (ks * 64 + krow * 2) ^ ((r & 7) << 4);
      const short8 af = *(const short8*)(lds + r * 512 + kb);
      accA[mt] = __builtin_amdgcn_mfma_f32_16x16x32_bf16(af, wfA[ks], accA[mt], 0, 0, 0);
      accB[mt] = __builtin_amdgcn_mfma_f32_16x16x32_bf16(af, wfB[ks], accB[mt], 0, 0, 0);
    }
  }

  // ---- epilogue: bias + relu -> per-wave bounce -> full 128B-line dwordx4 stores ----
  float* wb = (float*)(lds + L_BNC) + w * (16 * 36);
  const int dA = w * 32 + cl;
  const float bvA = bias[dA], bvB = bias[dA + 16];
  #pragma unroll
  for (int mt = 0; mt < 4; ++mt) {
    #pragma unroll
    for (int q = 0; q < 4; ++q) {
      const int r16 = (lane >> 4) * 4 + q;               // C/D: col=lane&15, row=(lane>>4)*4+q
      const float rsv = rsl[mt * 16 + r16];
      wb[r16 * 36 + cl]      = fmaxf(accA[mt][q] + rsv * bvA, 0.f);
      wb[r16 * 36 + 16 + cl] = fmaxf(accB[mt][q] + rsv * bvB, 0.f);
    }
    asm volatile("s_waitcnt lgkmcnt(0)" ::: "memory");   // wave-lockstep write visibility
    #pragma unroll
    for (int v = 0; v < 2; ++v) {
      const int i = lane * 2 + v;                        // 128 vec4 slots of 16x32 tile
      const int rI = i >> 3, cv = i & 7;
      const int n = n0 + mt * 16 + rI;
      if (n < NND)
        *(f32x4*)(out + ((size_t)bt * NND + n) * 256 + w * 32 + cv * 4) =
            *(const f32x4*)(wb + rI * 36 + cv * 4);
    }
  }
}

extern "C" void kernel_launch(void* const* d_in, const int* in_sizes, int n_in,
                              void* d_out, int out_size, void* d_ws, size_t ws_size,
                              hipStream_t stream) {
  const float* x  = (const float*)d_in[0];
  const float* Wm = (const float*)d_in[1];
  const float* b  = (const float*)d_in[2];
  const float* A  = (const float*)d_in[3];
  float* out = (float*)d_out;
  const int use_ws = (d_ws != nullptr && ws_size >= (size_t)WS_NEED) ? 1 : 0;
  if (use_ws) {
    prep_csr<<<(NROWP * 64 + 255) / 256, 256, 0, stream>>>(A, (char*)d_ws);
    prep_w<<<(16 * 8 * 64 + 255) / 256, 256, 0, stream>>>(Wm, (char*)d_ws);
  }
  gcn_main<<<GRID, 512, 0, stream>>>(x, Wm, b, A, out, (const char*)d_ws, use_ws);
}